// Round 7
// baseline (170.253 us; speedup 1.0000x reference)
//
#include <hip/hip_runtime.h>

#define NROWS 8192
#define HID   1024
#define NSAMP 8192
#define LCOLS 8193          // NSAMP + 1
#define NEG_INF_F (-1e37f)

#define SCALE_A 127         // E8M0: 2^0
#define SCALE_B 122         // E8M0: 2^-5  (W rows pre-scaled by 32)

typedef __attribute__((ext_vector_type(4)))  int   i32x4;
typedef __attribute__((ext_vector_type(8)))  int   i32x8;
typedef __attribute__((ext_vector_type(4)))  float f32x4;
typedef __attribute__((ext_vector_type(16))) float f32x16;
typedef f32x4 __attribute__((aligned(4))) f32x4u;   // 4B-aligned vector store
typedef __attribute__((ext_vector_type(8))) __bf16 bf16x8;
typedef __attribute__((ext_vector_type(8))) unsigned short u16x8;

__device__ __forceinline__ unsigned short f2bf(float x) {
  unsigned u = __float_as_uint(x);
  u += 0x7fffu + ((u >> 16) & 1u);
  return (unsigned short)(u >> 16);
}

#define GLOAD_LDS16(g, l)                                                      \
  __builtin_amdgcn_global_load_lds(                                            \
      (const __attribute__((address_space(1))) void*)(g),                      \
      (__attribute__((address_space(3))) void*)(l), 16, 0, 0)

// ============== fp8 workspace layout for 32x32x64 MFMA (lane-linear) =========
// Element (row = G*32 + (l&31), k = KK*64 + ((l>>5)&1)*32 + h*16 + j), j<16:
//   off = (G*16 + KK)*2048 + h*1024 + l*16 + j
// -> every ds_read_b128 is at LDS addr (lane*16): zero bank conflicts
//    (verified r3/r4: SQ_LDS_BANK_CONFLICT == 0).
// -> global_load_lds staging fully linear (2 KiB contiguous per (G,KK)).
// A and B use the SAME (lane,byte)->k map, so dot products are exact.

__device__ __forceinline__ int pk4(float a, float b, float c, float d) {
  int r = __builtin_amdgcn_cvt_pk_fp8_f32(a, b, 0, 0);
  r = __builtin_amdgcn_cvt_pk_fp8_f32(c, d, r, 1);
  return r;
}

// one thread per 16 ws bytes; 8 MB / 16 = 524288 threads
__global__ void k_cvtA(const float* __restrict__ A, unsigned char* __restrict__ Ab) {
  const int t = blockIdx.x * blockDim.x + threadIdx.x;
  const int l = t & 63, h = (t >> 6) & 1, KK = (t >> 7) & 15, G = t >> 11;
  const int row = G * 32 + (l & 31);
  const int k0 = KK * 64 + ((l >> 5) & 1) * 32 + h * 16;
  const float4* s = (const float4*)(A + (size_t)row * HID + k0);
  float4 f0 = s[0], f1 = s[1], f2 = s[2], f3 = s[3];
  int4 o;
  o.x = pk4(f0.x, f0.y, f0.z, f0.w);
  o.y = pk4(f1.x, f1.y, f1.z, f1.w);
  o.z = pk4(f2.x, f2.y, f2.z, f2.w);
  o.w = pk4(f3.x, f3.y, f3.z, f3.w);
  ((int4*)Ab)[t] = o;
}

__global__ void k_gatherB(const float* __restrict__ W, const int* __restrict__ sid,
                          unsigned char* __restrict__ Bb) {
  const int t = blockIdx.x * blockDim.x + threadIdx.x;
  const int l = t & 63, h = (t >> 6) & 1, KK = (t >> 7) & 15, G = t >> 11;
  const int srow = G * 32 + (l & 31);
  const int id = sid[srow];
  const int k0 = KK * 64 + ((l >> 5) & 1) * 32 + h * 16;
  const float4* s = (const float4*)(W + (size_t)id * HID + k0);
  float4 f0 = s[0], f1 = s[1], f2 = s[2], f3 = s[3];
  const float m = 32.0f;   // descaled in-HW by SCALE_B = 2^-5
  int4 o;
  o.x = pk4(f0.x * m, f0.y * m, f0.z * m, f0.w * m);
  o.y = pk4(f1.x * m, f1.y * m, f1.z * m, f1.w * m);
  o.z = pk4(f2.x * m, f2.y * m, f2.z * m, f2.w * m);
  o.w = pk4(f3.x * m, f3.y * m, f3.z * m, f3.w * m);
  ((int4*)Bb)[t] = o;
}

// ------------- true-class logits (column 0) + new_targets ----------------
__global__ void k_true(const float* __restrict__ X, const int* __restrict__ tgt,
                       const float* __restrict__ W, const float* __restrict__ bias,
                       const float* __restrict__ tfreq, float* __restrict__ out) {
  const int n = blockIdx.x * 4 + (threadIdx.x >> 6);
  const int l = threadIdx.x & 63;
  const int tg = tgt[n];
  float4 a = ((const float4*)(X + (size_t)n * HID))[l];
  float4 wv = ((const float4*)(W + (size_t)tg * HID))[l];
  float p = a.x * wv.x + a.y * wv.y + a.z * wv.z + a.w * wv.w;
  #pragma unroll
  for (int off = 32; off > 0; off >>= 1) p += __shfl_down(p, off);
  if (l == 0) {
    out[(size_t)n * LCOLS] = p + bias[tg] - __logf(tfreq[n]);
    ((int*)out)[(size_t)NROWS * LCOLS + n] = 0;
  }
}

// -- 128x128 MX-fp8 NT-GEMM: 32x32x64, BK=64, 3-buffer ring, counted vmcnt ----
__global__ __launch_bounds__(256, 3)
void k_gemm8(const unsigned char* __restrict__ Ab, const unsigned char* __restrict__ Bb,
             const int* __restrict__ tgt, const int* __restrict__ sid,
             const float* __restrict__ bias, const float* __restrict__ sfreq,
             float* __restrict__ out) {
  __shared__ unsigned char lds[49152];   // 3 ring buffers x (A 8K + B 8K)
  const int t = threadIdx.x, w = t >> 6, l = t & 63;

  // XCD swizzle with 16m x 32n chunks (B working set 4MB = one XCD L2)
  const int orig = blockIdx.y * 64 + blockIdx.x;     // 4096 blocks
  const int c = orig & 7, q = orig >> 3;             // chunk, within-chunk
  const int mi = (c >> 1) * 16 + (q >> 5);
  const int ni = (c & 1) * 32 + (q & 31);
  const int m0 = mi * 128, n0 = ni * 128;
  const int wm = w >> 1, wn = w & 1;
  f32x16 acc[2][2] = {};

  // wave w stages row-group G = (tile base) + w for both A and B
  const unsigned char* gA = Ab + ((size_t)(mi * 4 + w) * 16) * 2048 + l * 16;
  const unsigned char* gB = Bb + ((size_t)(ni * 4 + w) * 16) * 2048 + l * 16;

#define STAGE(buf_, KK_)                                                       \
  do {                                                                         \
    unsigned char* _d = lds + (buf_) * 16384 + w * 2048;                       \
    GLOAD_LDS16(gA + (KK_) * 2048,        _d);                                 \
    GLOAD_LDS16(gA + (KK_) * 2048 + 1024, _d + 1024);                          \
    GLOAD_LDS16(gB + (KK_) * 2048,        _d + 8192);                          \
    GLOAD_LDS16(gB + (KK_) * 2048 + 1024, _d + 8192 + 1024);                   \
  } while (0)

  // prologue: 2 stages in flight
  STAGE(0, 0);
  STAGE(1, 1);

  #pragma unroll
  for (int KK = 0; KK < 16; ++KK) {
    // wait for stage KK's 4 loads only; stages KK+1, KK+2 stay in flight
    // ACROSS the barrier (T4 counted vmcnt — never 0 in the main loop)
    if (KK < 15) asm volatile("s_waitcnt vmcnt(4)" ::: "memory");
    else         asm volatile("s_waitcnt vmcnt(0)" ::: "memory");
    __builtin_amdgcn_s_barrier();
    // WAR-safe: buffer (KK+2)%3 held stage KK-1, whose readers all consumed
    // their data (lgkmcnt before MFMA) before crossing the barrier above.
    if (KK < 14) STAGE((KK + 2) % 3, KK + 2);
    __builtin_amdgcn_sched_barrier(0);

    // fragment ds_reads from buffer KK%3 (addr = lane*16, conflict-free)
    const unsigned char* sAb = lds + (KK % 3) * 16384;
    const unsigned char* sBb = sAb + 8192;
    i32x4 aLo[2], aHi[2], bLo[2], bHi[2];
    #pragma unroll
    for (int mf = 0; mf < 2; ++mf) {
      aLo[mf] = *(const i32x4*)&sAb[(wm * 2 + mf) * 2048 + l * 16];
      aHi[mf] = *(const i32x4*)&sAb[(wm * 2 + mf) * 2048 + 1024 + l * 16];
    }
    #pragma unroll
    for (int nf = 0; nf < 2; ++nf) {
      bLo[nf] = *(const i32x4*)&sBb[(wn * 2 + nf) * 2048 + l * 16];
      bHi[nf] = *(const i32x4*)&sBb[(wn * 2 + nf) * 2048 + 1024 + l * 16];
    }
    __builtin_amdgcn_sched_barrier(0);

    // MFMA cluster: 4 x 32x32x64
    __builtin_amdgcn_s_setprio(1);
    #pragma unroll
    for (int mf = 0; mf < 2; ++mf) {
      const i32x8 af = (i32x8){aLo[mf][0], aLo[mf][1], aLo[mf][2], aLo[mf][3],
                               aHi[mf][0], aHi[mf][1], aHi[mf][2], aHi[mf][3]};
      #pragma unroll
      for (int nf = 0; nf < 2; ++nf) {
        const i32x8 bf = (i32x8){bLo[nf][0], bLo[nf][1], bLo[nf][2], bLo[nf][3],
                                 bHi[nf][0], bHi[nf][1], bHi[nf][2], bHi[nf][3]};
        acc[mf][nf] = __builtin_amdgcn_mfma_scale_f32_32x32x64_f8f6f4(
            af, bf, acc[mf][nf], 0, 0, 0, SCALE_A, 0, SCALE_B);
      }
    }
    __builtin_amdgcn_s_setprio(0);
  }
#undef STAGE

  // all waves done reading ring buffers before tile overwrite (loop now has
  // its barrier at iteration TOP, so this is required)
  __syncthreads();

  // ---- epilogue: two 64-row halves restaged in LDS, 512B row stores ----
  // C/D map (32x32, verified m74/m101): col=lane&31, row=(reg&3)+8*(reg>>2)+4*(lane>>5)
  float* tile = (float*)lds;   // 64 rows x 128 cols f32 = 32 KB
  #pragma unroll
  for (int half = 0; half < 2; ++half) {
    if (half) __syncthreads();          // prior stores' LDS reads complete
    if (wm == half) {
      #pragma unroll
      for (int nf = 0; nf < 2; ++nf) {
        const int col = wn * 64 + nf * 32 + (l & 31);
        const int gcol = n0 + col;
        const int sv = sid[gcol];
        const float sbv = bias[sv] - __logf(sfreq[gcol]);
        #pragma unroll
        for (int mf = 0; mf < 2; ++mf) {
          #pragma unroll
          for (int i = 0; i < 16; ++i) {
            const int r = mf * 32 + (i & 3) + 8 * (i >> 2) + 4 * (l >> 5);
            float cv = acc[mf][nf][i] + sbv;
            if (tgt[m0 + half * 64 + r] == sv) cv = NEG_INF_F;
            tile[r * 128 + (col ^ ((r & 4) << 2))] = cv;   // 2-way banks: free
          }
        }
      }
    }
    __syncthreads();
    #pragma unroll
    for (int p = 0; p < 8; ++p) {
      const int idx = p * 256 + t;
      const int r = idx >> 5;                        // local row 0..63
      const int c16 = idx & 31;                      // 16B unit within row
      f32x4 v = *(const f32x4*)&tile[r * 128 + ((c16 * 4) ^ ((r & 4) << 2))];
      *(f32x4u*)&out[(size_t)(m0 + half * 64 + r) * LCOLS + 1 + n0 + c16 * 4] = v;
    }
  }
}

// ---------------- bf16 fallback (round-1 verified), no workspace ----------------
__device__ __forceinline__ void pack8(unsigned short* p, float4 a, float4 b) {
  u16x8 v;
  v[0] = f2bf(a.x); v[1] = f2bf(a.y); v[2] = f2bf(a.z); v[3] = f2bf(a.w);
  v[4] = f2bf(b.x); v[5] = f2bf(b.y); v[6] = f2bf(b.z); v[7] = f2bf(b.w);
  *(u16x8*)p = v;
}

__global__ __launch_bounds__(256)
void k_gemm_fb(const float* __restrict__ Af, const float* __restrict__ W,
               const int* __restrict__ tgt, const int* __restrict__ sid,
               const float* __restrict__ bias, const float* __restrict__ sfreq,
               float* __restrict__ out) {
  __shared__ unsigned short sA[128 * 32];
  __shared__ unsigned short sB[128 * 32];
  const int t = threadIdx.x;
  const int w = t >> 6, l = t & 63;
  const int m0 = blockIdx.y * 128, n0 = blockIdx.x * 128;
  const int wm = w >> 1, wn = w & 1;
  f32x4 acc[4][4] = {};
  const int srow = w * 16 + (l >> 2);
  const int scol = (l & 3) * 8;

  const int id0 = sid[n0 + srow], id1 = sid[n0 + 64 + srow];
  const float* gaf0 = Af + (size_t)(m0 + srow) * HID + scol;
  const float* gaf1 = gaf0 + (size_t)64 * HID;
  const float* gbf0 = W + (size_t)id0 * HID + scol;
  const float* gbf1 = W + (size_t)id1 * HID + scol;
  for (int kk = 0; kk < HID; kk += 32) {
    float4 a0 = *(const float4*)(gaf0 + kk), a1 = *(const float4*)(gaf0 + kk + 4);
    float4 a2 = *(const float4*)(gaf1 + kk), a3 = *(const float4*)(gaf1 + kk + 4);
    float4 b0 = *(const float4*)(gbf0 + kk), b1 = *(const float4*)(gbf0 + kk + 4);
    float4 b2 = *(const float4*)(gbf1 + kk), b3 = *(const float4*)(gbf1 + kk + 4);
    __syncthreads();
    pack8(&sA[t * 8], a0, a1);
    pack8(&sA[2048 + t * 8], a2, a3);
    pack8(&sB[t * 8], b0, b1);
    pack8(&sB[2048 + t * 8], b2, b3);
    __syncthreads();
    bf16x8 af_[4], bf_[4];
    const int rl_ = l & 15, kq_ = l >> 4;
    #pragma unroll
    for (int m = 0; m < 4; m++)
      af_[m] = *(const bf16x8*)&sA[(wm * 64 + m * 16 + rl_) * 32 + kq_ * 8];
    #pragma unroll
    for (int n = 0; n < 4; n++)
      bf_[n] = *(const bf16x8*)&sB[(wn * 64 + n * 16 + rl_) * 32 + kq_ * 8];
    #pragma unroll
    for (int m = 0; m < 4; m++)
      #pragma unroll
      for (int n = 0; n < 4; n++)
        acc[m][n] = __builtin_amdgcn_mfma_f32_16x16x32_bf16(af_[m], bf_[n],
                                                            acc[m][n], 0, 0, 0);
  }
  const int rl = l & 15, rq = l >> 4;
  #pragma unroll
  for (int n = 0; n < 4; ++n) {
    const int col = n0 + wn * 64 + n * 16 + rl;
    const int sv = sid[col];
    const float sbv = bias[sv] - __logf(sfreq[col]);
    #pragma unroll
    for (int m = 0; m < 4; ++m) {
      const int rbase = m0 + wm * 64 + m * 16 + rq * 4;
      #pragma unroll
      for (int i = 0; i < 4; ++i) {
        const int r = rbase + i;
        float c = acc[m][n][i] + sbv;
        if (tgt[r] == sv) c = NEG_INF_F;
        out[(size_t)r * LCOLS + 1 + col] = c;
      }
    }
  }
}

extern "C" void kernel_launch(void* const* d_in, const int* in_sizes, int n_in,
                              void* d_out, int out_size, void* d_ws, size_t ws_size,
                              hipStream_t stream) {
  (void)in_sizes; (void)n_in; (void)out_size;
  const float* output      = (const float*)d_in[0];
  const int*   targets     = (const int*)d_in[1];
  const int*   sample_ids  = (const int*)d_in[2];
  const float* true_freq   = (const float*)d_in[3];
  const float* sample_freq = (const float*)d_in[4];
  const float* weight      = (const float*)d_in[5];
  const float* bias        = (const float*)d_in[6];
  float* out = (float*)d_out;

  const size_t needA = (size_t)NROWS * HID;   // 8 MB fp8
  const size_t needB = (size_t)NSAMP * HID;   // 8 MB fp8
  const bool use_ws = ws_size >= (needA + needB);

  k_true<<<NROWS / 4, 256, 0, stream>>>(output, targets, weight, bias, true_freq, out);

  dim3 grid(NSAMP / 128, NROWS / 128);
  if (use_ws) {
    unsigned char* Ab = (unsigned char*)d_ws;
    unsigned char* Bb = Ab + needA;
    k_cvtA<<<2048, 256, 0, stream>>>(output, Ab);
    k_gatherB<<<2048, 256, 0, stream>>>(weight, sample_ids, Bb);
    k_gemm8<<<grid, 256, 0, stream>>>(Ab, Bb, targets, sample_ids, bias,
                                      sample_freq, out);
  } else {
    k_gemm_fb<<<grid, 256, 0, stream>>>(output, weight, targets, sample_ids,
                                        bias, sample_freq, out);
  }
}

// Round 8
// 148.836 us; speedup vs baseline: 1.1439x; 1.1439x over previous
//
#include <hip/hip_runtime.h>

#define NROWS 8192
#define HID   1024
#define NSAMP 8192
#define LCOLS 8193          // NSAMP + 1
#define NEG_INF_F (-1e37f)

#define SCALE_A 127         // E8M0: 2^0
#define SCALE_B 122         // E8M0: 2^-5  (W rows pre-scaled by 32)

typedef __attribute__((ext_vector_type(4)))  int   i32x4;
typedef __attribute__((ext_vector_type(8)))  int   i32x8;
typedef __attribute__((ext_vector_type(4)))  float f32x4;
typedef __attribute__((ext_vector_type(16))) float f32x16;
typedef f32x4 __attribute__((aligned(4))) f32x4u;   // 4B-aligned vector store
typedef __attribute__((ext_vector_type(8))) __bf16 bf16x8;
typedef __attribute__((ext_vector_type(8))) unsigned short u16x8;

__device__ __forceinline__ unsigned short f2bf(float x) {
  unsigned u = __float_as_uint(x);
  u += 0x7fffu + ((u >> 16) & 1u);
  return (unsigned short)(u >> 16);
}

#define GLOAD_LDS16(g, l)                                                      \
  __builtin_amdgcn_global_load_lds(                                            \
      (const __attribute__((address_space(1))) void*)(g),                      \
      (__attribute__((address_space(3))) void*)(l), 16, 0, 0)

// ============== fp8 workspace layout for 32x32x64 MFMA (lane-linear) =========
// Element (row = G*32 + (l&31), k = KK*64 + ((l>>5)&1)*32 + h*16 + j), j<16:
//   off = (G*16 + KK)*2048 + h*1024 + l*16 + j
// -> every ds_read_b128 is at LDS addr (lane*16): zero bank conflicts
//    (verified r3-r5: SQ_LDS_BANK_CONFLICT == 0).
// -> global_load_lds staging fully linear (2 KiB contiguous per (G,KK)).
// A and B use the SAME (lane,byte)->k map, so dot products are exact.

__device__ __forceinline__ int pk4(float a, float b, float c, float d) {
  int r = __builtin_amdgcn_cvt_pk_fp8_f32(a, b, 0, 0);
  r = __builtin_amdgcn_cvt_pk_fp8_f32(c, d, r, 1);
  return r;
}

// merged A-convert + B-gather: one dispatch (saves a launch gap).
// blocks [0,2048): A path; [2048,4096): B path. One thread per 16 ws bytes.
__global__ void k_pack(const float* __restrict__ A, const float* __restrict__ W,
                       const int* __restrict__ sid,
                       unsigned char* __restrict__ Ab, unsigned char* __restrict__ Bb) {
  const int bid = blockIdx.x;
  if (bid < 2048) {
    const int t = bid * 256 + threadIdx.x;
    const int l = t & 63, h = (t >> 6) & 1, KK = (t >> 7) & 15, G = t >> 11;
    const int row = G * 32 + (l & 31);
    const int k0 = KK * 64 + ((l >> 5) & 1) * 32 + h * 16;
    const float4* s = (const float4*)(A + (size_t)row * HID + k0);
    float4 f0 = s[0], f1 = s[1], f2 = s[2], f3 = s[3];
    int4 o;
    o.x = pk4(f0.x, f0.y, f0.z, f0.w);
    o.y = pk4(f1.x, f1.y, f1.z, f1.w);
    o.z = pk4(f2.x, f2.y, f2.z, f2.w);
    o.w = pk4(f3.x, f3.y, f3.z, f3.w);
    ((int4*)Ab)[t] = o;
  } else {
    const int t = (bid - 2048) * 256 + threadIdx.x;
    const int l = t & 63, h = (t >> 6) & 1, KK = (t >> 7) & 15, G = t >> 11;
    const int srow = G * 32 + (l & 31);
    const int id = sid[srow];
    const int k0 = KK * 64 + ((l >> 5) & 1) * 32 + h * 16;
    const float4* s = (const float4*)(W + (size_t)id * HID + k0);
    float4 f0 = s[0], f1 = s[1], f2 = s[2], f3 = s[3];
    const float m = 32.0f;   // descaled in-HW by SCALE_B = 2^-5
    int4 o;
    o.x = pk4(f0.x * m, f0.y * m, f0.z * m, f0.w * m);
    o.y = pk4(f1.x * m, f1.y * m, f1.z * m, f1.w * m);
    o.z = pk4(f2.x * m, f2.y * m, f2.z * m, f2.w * m);
    o.w = pk4(f3.x * m, f3.y * m, f3.z * m, f3.w * m);
    ((int4*)Bb)[t] = o;
  }
}

// ------------- true-class logits (column 0) + new_targets ----------------
__global__ void k_true(const float* __restrict__ X, const int* __restrict__ tgt,
                       const float* __restrict__ W, const float* __restrict__ bias,
                       const float* __restrict__ tfreq, float* __restrict__ out) {
  const int n = blockIdx.x * 4 + (threadIdx.x >> 6);
  const int l = threadIdx.x & 63;
  const int tg = tgt[n];
  float4 a = ((const float4*)(X + (size_t)n * HID))[l];
  float4 wv = ((const float4*)(W + (size_t)tg * HID))[l];
  float p = a.x * wv.x + a.y * wv.y + a.z * wv.z + a.w * wv.w;
  #pragma unroll
  for (int off = 32; off > 0; off >>= 1) p += __shfl_down(p, off);
  if (l == 0) {
    out[(size_t)n * LCOLS] = p + bias[tg] - __logf(tfreq[n]);
    ((int*)out)[(size_t)NROWS * LCOLS + n] = 0;
  }
}

// -- 128x128 MX-fp8 NT-GEMM: 32x32x64, BK=64, 2-phase (r6 verified) + nt-store -
__global__ __launch_bounds__(256, 3)
void k_gemm8(const unsigned char* __restrict__ Ab, const unsigned char* __restrict__ Bb,
             const int* __restrict__ tgt, const int* __restrict__ sid,
             const float* __restrict__ bias, const float* __restrict__ sfreq,
             float* __restrict__ out) {
  __shared__ unsigned char lds[32768];   // dbuf 2x(A 8K + B 8K); epilogue: 64x128 f32
  const int t = threadIdx.x, w = t >> 6, l = t & 63;

  // XCD swizzle with 16m x 32n chunks (B working set 4MB = one XCD L2)
  const int orig = blockIdx.y * 64 + blockIdx.x;     // 4096 blocks
  const int c = orig & 7, q = orig >> 3;             // chunk, within-chunk
  const int mi = (c >> 1) * 16 + (q >> 5);
  const int ni = (c & 1) * 32 + (q & 31);
  const int m0 = mi * 128, n0 = ni * 128;
  const int wm = w >> 1, wn = w & 1;
  f32x16 acc[2][2] = {};

  // wave w stages row-group G = (tile base) + w for both A and B
  const unsigned char* gA = Ab + ((size_t)(mi * 4 + w) * 16) * 2048 + l * 16;
  const unsigned char* gB = Bb + ((size_t)(ni * 4 + w) * 16) * 2048 + l * 16;

#define STAGE(buf_, KK_)                                                       \
  do {                                                                         \
    unsigned char* _d = lds + (buf_) * 16384 + w * 2048;                       \
    GLOAD_LDS16(gA + (KK_) * 2048,        _d);                                 \
    GLOAD_LDS16(gA + (KK_) * 2048 + 1024, _d + 1024);                          \
    GLOAD_LDS16(gB + (KK_) * 2048,        _d + 8192);                          \
    GLOAD_LDS16(gB + (KK_) * 2048 + 1024, _d + 8192 + 1024);                   \
  } while (0)

  STAGE(0, 0);
  asm volatile("s_waitcnt vmcnt(0)" ::: "memory");
  __builtin_amdgcn_s_barrier();

  int buf = 0;
  for (int KK = 0; KK < 16; ++KK) {
    // 1) prefetch next K-step into the other buffer
    if (KK < 15) STAGE(buf ^ 1, KK + 1);
    __builtin_amdgcn_sched_barrier(0);

    // 2) fragment ds_reads from current buffer (addr = lane*16, conflict-free)
    const unsigned char* sAb = lds + buf * 16384;
    const unsigned char* sBb = sAb + 8192;
    i32x4 aLo[2], aHi[2], bLo[2], bHi[2];
    #pragma unroll
    for (int mf = 0; mf < 2; ++mf) {
      aLo[mf] = *(const i32x4*)&sAb[(wm * 2 + mf) * 2048 + l * 16];
      aHi[mf] = *(const i32x4*)&sAb[(wm * 2 + mf) * 2048 + 1024 + l * 16];
    }
    #pragma unroll
    for (int nf = 0; nf < 2; ++nf) {
      bLo[nf] = *(const i32x4*)&sBb[(wn * 2 + nf) * 2048 + l * 16];
      bHi[nf] = *(const i32x4*)&sBb[(wn * 2 + nf) * 2048 + 1024 + l * 16];
    }
    __builtin_amdgcn_sched_barrier(0);

    // 3) MFMA cluster: 4 x 32x32x64
    __builtin_amdgcn_s_setprio(1);
    #pragma unroll
    for (int mf = 0; mf < 2; ++mf) {
      const i32x8 af = (i32x8){aLo[mf][0], aLo[mf][1], aLo[mf][2], aLo[mf][3],
                               aHi[mf][0], aHi[mf][1], aHi[mf][2], aHi[mf][3]};
      #pragma unroll
      for (int nf = 0; nf < 2; ++nf) {
        const i32x8 bf = (i32x8){bLo[nf][0], bLo[nf][1], bLo[nf][2], bLo[nf][3],
                                 bHi[nf][0], bHi[nf][1], bHi[nf][2], bHi[nf][3]};
        acc[mf][nf] = __builtin_amdgcn_mfma_scale_f32_32x32x64_f8f6f4(
            af, bf, acc[mf][nf], 0, 0, 0, SCALE_A, 0, SCALE_B);
      }
    }
    __builtin_amdgcn_s_setprio(0);

    // 4) single drain + barrier per K-step
    asm volatile("s_waitcnt vmcnt(0)" ::: "memory");
    __builtin_amdgcn_s_barrier();
    buf ^= 1;
  }
#undef STAGE

  // ---- epilogue: two 64-row halves restaged in LDS, 512B row nt-stores ----
  // C/D map (32x32, verified m74/m101): col=lane&31, row=(reg&3)+8*(reg>>2)+4*(lane>>5)
  // nt flag: output is write-once/read-never here -> evict-first, so the
  // 268 MB write stream stops flushing the A/B panels out of L2/L3.
  float* tile = (float*)lds;   // 64 rows x 128 cols f32 = 32 KB
  #pragma unroll
  for (int half = 0; half < 2; ++half) {
    if (half) __syncthreads();          // prior stores' LDS reads complete
    if (wm == half) {
      #pragma unroll
      for (int nf = 0; nf < 2; ++nf) {
        const int col = wn * 64 + nf * 32 + (l & 31);
        const int gcol = n0 + col;
        const int sv = sid[gcol];
        const float sbv = bias[sv] - __logf(sfreq[gcol]);
        #pragma unroll
        for (int mf = 0; mf < 2; ++mf) {
          #pragma unroll
          for (int i = 0; i < 16; ++i) {
            const int r = mf * 32 + (i & 3) + 8 * (i >> 2) + 4 * (l >> 5);
            float cv = acc[mf][nf][i] + sbv;
            if (tgt[m0 + half * 64 + r] == sv) cv = NEG_INF_F;
            tile[r * 128 + (col ^ ((r & 4) << 2))] = cv;   // 2-way banks: free
          }
        }
      }
    }
    __syncthreads();
    #pragma unroll
    for (int p = 0; p < 8; ++p) {
      const int idx = p * 256 + t;
      const int r = idx >> 5;                        // local row 0..63
      const int c16 = idx & 31;                      // 16B unit within row
      f32x4 v = *(const f32x4*)&tile[r * 128 + ((c16 * 4) ^ ((r & 4) << 2))];
      __builtin_nontemporal_store(
          v, (f32x4u*)&out[(size_t)(m0 + half * 64 + r) * LCOLS + 1 + n0 + c16 * 4]);
    }
  }
}

// ---------------- bf16 fallback (round-1 verified), no workspace ----------------
__device__ __forceinline__ void pack8(unsigned short* p, float4 a, float4 b) {
  u16x8 v;
  v[0] = f2bf(a.x); v[1] = f2bf(a.y); v[2] = f2bf(a.z); v[3] = f2bf(a.w);
  v[4] = f2bf(b.x); v[5] = f2bf(b.y); v[6] = f2bf(b.z); v[7] = f2bf(b.w);
  *(u16x8*)p = v;
}

__global__ __launch_bounds__(256)
void k_gemm_fb(const float* __restrict__ Af, const float* __restrict__ W,
               const int* __restrict__ tgt, const int* __restrict__ sid,
               const float* __restrict__ bias, const float* __restrict__ sfreq,
               float* __restrict__ out) {
  __shared__ unsigned short sA[128 * 32];
  __shared__ unsigned short sB[128 * 32];
  const int t = threadIdx.x;
  const int w = t >> 6, l = t & 63;
  const int m0 = blockIdx.y * 128, n0 = blockIdx.x * 128;
  const int wm = w >> 1, wn = w & 1;
  f32x4 acc[4][4] = {};
  const int srow = w * 16 + (l >> 2);
  const int scol = (l & 3) * 8;

  const int id0 = sid[n0 + srow], id1 = sid[n0 + 64 + srow];
  const float* gaf0 = Af + (size_t)(m0 + srow) * HID + scol;
  const float* gaf1 = gaf0 + (size_t)64 * HID;
  const float* gbf0 = W + (size_t)id0 * HID + scol;
  const float* gbf1 = W + (size_t)id1 * HID + scol;
  for (int kk = 0; kk < HID; kk += 32) {
    float4 a0 = *(const float4*)(gaf0 + kk), a1 = *(const float4*)(gaf0 + kk + 4);
    float4 a2 = *(const float4*)(gaf1 + kk), a3 = *(const float4*)(gaf1 + kk + 4);
    float4 b0 = *(const float4*)(gbf0 + kk), b1 = *(const float4*)(gbf0 + kk + 4);
    float4 b2 = *(const float4*)(gbf1 + kk), b3 = *(const float4*)(gbf1 + kk + 4);
    __syncthreads();
    pack8(&sA[t * 8], a0, a1);
    pack8(&sA[2048 + t * 8], a2, a3);
    pack8(&sB[t * 8], b0, b1);
    pack8(&sB[2048 + t * 8], b2, b3);
    __syncthreads();
    bf16x8 af_[4], bf_[4];
    const int rl_ = l & 15, kq_ = l >> 4;
    #pragma unroll
    for (int m = 0; m < 4; m++)
      af_[m] = *(const bf16x8*)&sA[(wm * 64 + m * 16 + rl_) * 32 + kq_ * 8];
    #pragma unroll
    for (int n = 0; n < 4; n++)
      bf_[n] = *(const bf16x8*)&sB[(wn * 64 + n * 16 + rl_) * 32 + kq_ * 8];
    #pragma unroll
    for (int m = 0; m < 4; m++)
      #pragma unroll
      for (int n = 0; n < 4; n++)
        acc[m][n] = __builtin_amdgcn_mfma_f32_16x16x32_bf16(af_[m], bf_[n],
                                                            acc[m][n], 0, 0, 0);
  }
  const int rl = l & 15, rq = l >> 4;
  #pragma unroll
  for (int n = 0; n < 4; ++n) {
    const int col = n0 + wn * 64 + n * 16 + rl;
    const int sv = sid[col];
    const float sbv = bias[sv] - __logf(sfreq[col]);
    #pragma unroll
    for (int m = 0; m < 4; ++m) {
      const int rbase = m0 + wm * 64 + m * 16 + rq * 4;
      #pragma unroll
      for (int i = 0; i < 4; ++i) {
        const int r = rbase + i;
        float c = acc[m][n][i] + sbv;
        if (tgt[r] == sv) c = NEG_INF_F;
        out[(size_t)r * LCOLS + 1 + col] = c;
      }
    }
  }
}

extern "C" void kernel_launch(void* const* d_in, const int* in_sizes, int n_in,
                              void* d_out, int out_size, void* d_ws, size_t ws_size,
                              hipStream_t stream) {
  (void)in_sizes; (void)n_in; (void)out_size;
  const float* output      = (const float*)d_in[0];
  const int*   targets     = (const int*)d_in[1];
  const int*   sample_ids  = (const int*)d_in[2];
  const float* true_freq   = (const float*)d_in[3];
  const float* sample_freq = (const float*)d_in[4];
  const float* weight      = (const float*)d_in[5];
  const float* bias        = (const float*)d_in[6];
  float* out = (float*)d_out;

  const size_t needA = (size_t)NROWS * HID;   // 8 MB fp8
  const size_t needB = (size_t)NSAMP * HID;   // 8 MB fp8
  const bool use_ws = ws_size >= (needA + needB);

  k_true<<<NROWS / 4, 256, 0, stream>>>(output, targets, weight, bias, true_freq, out);

  dim3 grid(NSAMP / 128, NROWS / 128);
  if (use_ws) {
    unsigned char* Ab = (unsigned char*)d_ws;
    unsigned char* Bb = Ab + needA;
    k_pack<<<4096, 256, 0, stream>>>(output, weight, sample_ids, Ab, Bb);
    k_gemm8<<<grid, 256, 0, stream>>>(Ab, Bb, targets, sample_ids, bias,
                                      sample_freq, out);
  } else {
    k_gemm_fb<<<grid, 256, 0, stream>>>(output, weight, targets, sample_ids,
                                        bias, sample_freq, out);
  }
}

// Round 9
// 120.463 us; speedup vs baseline: 1.4133x; 1.2355x over previous
//
#include <hip/hip_runtime.h>

#define NROWS 8192
#define HID   1024
#define NSAMP 8192
#define LCOLS 8193          // NSAMP + 1
#define NEG_INF_F (-1e37f)

#define SCALE_A 127         // E8M0: 2^0
#define SCALE_B 122         // E8M0: 2^-5  (W rows pre-scaled by 32)

typedef __attribute__((ext_vector_type(4)))  int   i32x4;
typedef __attribute__((ext_vector_type(8)))  int   i32x8;
typedef __attribute__((ext_vector_type(4)))  float f32x4;
typedef __attribute__((ext_vector_type(16))) float f32x16;
typedef f32x4 __attribute__((aligned(4))) f32x4u;   // 4B-aligned vector store
typedef __attribute__((ext_vector_type(8))) __bf16 bf16x8;
typedef __attribute__((ext_vector_type(8))) unsigned short u16x8;

__device__ __forceinline__ unsigned short f2bf(float x) {
  unsigned u = __float_as_uint(x);
  u += 0x7fffu + ((u >> 16) & 1u);
  return (unsigned short)(u >> 16);
}

#define GLOAD_LDS16(g, l)                                                      \
  __builtin_amdgcn_global_load_lds(                                            \
      (const __attribute__((address_space(1))) void*)(g),                      \
      (__attribute__((address_space(3))) void*)(l), 16, 0, 0)

// ============== fp4 workspace layout for 32x32x64 MFMA (lane-linear) =========
// Element (row = G*32 + (l&31), k = KK*64 + (l>>5)*32 + j), j<32, packed two
// per byte (low nibble = even j):
//   byte off = (G*16 + KK)*1024 + l*16 + j/2
// -> every ds_read_b128 is at LDS addr (lane*16): zero bank conflicts
//    (pattern verified r3-r5: SQ_LDS_BANK_CONFLICT == 0).
// -> global_load_lds staging fully linear (1 KiB contiguous per (G,KK)).
// A and B use the SAME (lane,nibble)->k map, so any within-lane k-permutation
// (including nibble order) cancels in the dot product.

// fp4 e2m1 quantize (grid 0,.5,1,1.5,2,3,4,6; round to nearest)
__device__ __forceinline__ unsigned fp4nib(float x) {
  unsigned s = (__float_as_uint(x) >> 31) << 3;
  float y = fabsf(x);
  unsigned n = y < 0.25f ? 0u : y < 0.75f ? 1u : y < 1.25f ? 2u :
               y < 1.75f ? 3u : y < 2.5f  ? 4u : y < 3.5f  ? 5u :
               y < 5.0f  ? 6u : 7u;
  return n | s;
}

__device__ __forceinline__ unsigned long long pk16(const float* e, float m) {
  unsigned long long r = 0;
  #pragma unroll
  for (int i = 0; i < 8; ++i) {
    unsigned long long b =
        fp4nib(e[2 * i] * m) | (fp4nib(e[2 * i + 1] * m) << 4);
    r |= b << (8 * i);
  }
  return r;
}

// merged prep: blocks [0,2048) A-pack, [2048,4096) B-pack, [4096,6144) true.
// pack: one thread per 8 ws bytes = 16 elements (reads 4x float4 = 64 B).
__global__ void k_prep(const float* __restrict__ A, const float* __restrict__ W,
                       const int* __restrict__ sid, const int* __restrict__ tgt,
                       const float* __restrict__ bias, const float* __restrict__ tfreq,
                       unsigned char* __restrict__ Ab, unsigned char* __restrict__ Bb,
                       float* __restrict__ out) {
  const int bid = blockIdx.x;
  if (bid < 4096) {
    const bool isA = bid < 2048;
    const int t = (isA ? bid : bid - 2048) * 256 + threadIdx.x;
    const int BI = t >> 7;                    // (G*16 + KK)
    const int l = (t & 127) >> 1;             // lane 0..63
    const int j0 = (t & 1) * 16;              // nibble start within lane slice
    const int row = (BI >> 4) * 32 + (l & 31);
    const int k0 = (BI & 15) * 64 + (l >> 5) * 32 + j0;
    const float* src = isA ? (A + (size_t)row * HID + k0)
                           : (W + (size_t)sid[row] * HID + k0);
    float e[16];
    #pragma unroll
    for (int v = 0; v < 4; ++v) {
      float4 f = ((const float4*)src)[v];
      e[v * 4 + 0] = f.x; e[v * 4 + 1] = f.y; e[v * 4 + 2] = f.z; e[v * 4 + 3] = f.w;
    }
    unsigned long long r = pk16(e, isA ? 1.0f : 32.0f);
    ((unsigned long long*)(isA ? Ab : Bb))[t] = r;
  } else {
    // true-class logits (column 0) + new_targets; one wave per row
    const int n = (bid - 4096) * 4 + (threadIdx.x >> 6);
    const int l = threadIdx.x & 63;
    const int tg = tgt[n];
    float4 a = ((const float4*)(A + (size_t)n * HID))[l];
    float4 wv = ((const float4*)(W + (size_t)tg * HID))[l];
    float p = a.x * wv.x + a.y * wv.y + a.z * wv.z + a.w * wv.w;
    #pragma unroll
    for (int off = 32; off > 0; off >>= 1) p += __shfl_down(p, off);
    if (l == 0) {
      out[(size_t)n * LCOLS] = p + bias[tg] - __logf(tfreq[n]);
      ((int*)out)[(size_t)NROWS * LCOLS + n] = 0;
    }
  }
}

// -- 128x128 MX-fp4 NT-GEMM: 32x32x64, BK=64, 2-phase (r6 verified) + nt-store -
__global__ __launch_bounds__(256, 4)
void k_gemm4(const unsigned char* __restrict__ Ab, const unsigned char* __restrict__ Bb,
             const int* __restrict__ tgt, const int* __restrict__ sid,
             const float* __restrict__ bias, const float* __restrict__ sfreq,
             float* __restrict__ out) {
  __shared__ unsigned char lds[32768];   // dbuf 2x(A 4K + B 4K) = 16K; epilogue: 64x128 f32
  const int t = threadIdx.x, w = t >> 6, l = t & 63;

  // XCD swizzle with 16m x 32n chunks (B working set fits one XCD L2)
  const int orig = blockIdx.y * 64 + blockIdx.x;     // 4096 blocks
  const int c = orig & 7, q = orig >> 3;             // chunk, within-chunk
  const int mi = (c >> 1) * 16 + (q >> 5);
  const int ni = (c & 1) * 32 + (q & 31);
  const int m0 = mi * 128, n0 = ni * 128;
  const int wm = w >> 1, wn = w & 1;
  f32x16 acc[2][2] = {};

  // wave w stages row-group G = (tile base) + w for both A and B
  const unsigned char* gA = Ab + ((size_t)(mi * 4 + w) * 16) * 1024 + l * 16;
  const unsigned char* gB = Bb + ((size_t)(ni * 4 + w) * 16) * 1024 + l * 16;

#define STAGE(buf_, KK_)                                                       \
  do {                                                                         \
    unsigned char* _d = lds + (buf_) * 8192 + w * 1024;                        \
    GLOAD_LDS16(gA + (KK_) * 1024, _d);                                        \
    GLOAD_LDS16(gB + (KK_) * 1024, _d + 4096);                                 \
  } while (0)

  STAGE(0, 0);
  asm volatile("s_waitcnt vmcnt(0)" ::: "memory");
  __builtin_amdgcn_s_barrier();

  int buf = 0;
  for (int KK = 0; KK < 16; ++KK) {
    // 1) prefetch next K-step into the other buffer
    if (KK < 15) STAGE(buf ^ 1, KK + 1);
    __builtin_amdgcn_sched_barrier(0);

    // 2) fragment ds_reads from current buffer (addr = lane*16, conflict-free)
    const unsigned char* sAb = lds + buf * 8192;
    const unsigned char* sBb = sAb + 4096;
    i32x4 aF[2], bF[2];
    #pragma unroll
    for (int mf = 0; mf < 2; ++mf)
      aF[mf] = *(const i32x4*)&sAb[(wm * 2 + mf) * 1024 + l * 16];
    #pragma unroll
    for (int nf = 0; nf < 2; ++nf)
      bF[nf] = *(const i32x4*)&sBb[(wn * 2 + nf) * 1024 + l * 16];
    __builtin_amdgcn_sched_barrier(0);

    // 3) MFMA cluster: 4 x 32x32x64, fp4 format (cbsz=4, blgp=4; upper 4
    //    operand regs unused by fp4)
    __builtin_amdgcn_s_setprio(1);
    #pragma unroll
    for (int mf = 0; mf < 2; ++mf) {
      const i32x8 af = (i32x8){aF[mf][0], aF[mf][1], aF[mf][2], aF[mf][3],
                               0, 0, 0, 0};
      #pragma unroll
      for (int nf = 0; nf < 2; ++nf) {
        const i32x8 bf = (i32x8){bF[nf][0], bF[nf][1], bF[nf][2], bF[nf][3],
                                 0, 0, 0, 0};
        acc[mf][nf] = __builtin_amdgcn_mfma_scale_f32_32x32x64_f8f6f4(
            af, bf, acc[mf][nf], 4, 4, 0, SCALE_A, 0, SCALE_B);
      }
    }
    __builtin_amdgcn_s_setprio(0);

    // 4) single drain + barrier per K-step
    asm volatile("s_waitcnt vmcnt(0)" ::: "memory");
    __builtin_amdgcn_s_barrier();
    buf ^= 1;
  }
#undef STAGE

  // ---- epilogue: two 64-row halves restaged in LDS, 512B row nt-stores ----
  // C/D map (32x32, verified m74/m101): col=lane&31, row=(reg&3)+8*(reg>>2)+4*(lane>>5)
  float* tile = (float*)lds;   // 64 rows x 128 cols f32 = 32 KB
  #pragma unroll
  for (int half = 0; half < 2; ++half) {
    if (half) __syncthreads();          // prior stores' LDS reads complete
    if (wm == half) {
      #pragma unroll
      for (int nf = 0; nf < 2; ++nf) {
        const int col = wn * 64 + nf * 32 + (l & 31);
        const int gcol = n0 + col;
        const int sv = sid[gcol];
        const float sbv = bias[sv] - __logf(sfreq[gcol]);
        #pragma unroll
        for (int mf = 0; mf < 2; ++mf) {
          #pragma unroll
          for (int i = 0; i < 16; ++i) {
            const int r = mf * 32 + (i & 3) + 8 * (i >> 2) + 4 * (l >> 5);
            float cv = acc[mf][nf][i] + sbv;
            if (tgt[m0 + half * 64 + r] == sv) cv = NEG_INF_F;
            tile[r * 128 + (col ^ ((r & 4) << 2))] = cv;   // 2-way banks: free
          }
        }
      }
    }
    __syncthreads();
    #pragma unroll
    for (int p = 0; p < 8; ++p) {
      const int idx = p * 256 + t;
      const int r = idx >> 5;                        // local row 0..63
      const int c16 = idx & 31;                      // 16B unit within row
      f32x4 v = *(const f32x4*)&tile[r * 128 + ((c16 * 4) ^ ((r & 4) << 2))];
      __builtin_nontemporal_store(
          v, (f32x4u*)&out[(size_t)(m0 + half * 64 + r) * LCOLS + 1 + n0 + c16 * 4]);
    }
  }
}

// ---------------- bf16 fallback (round-1 verified), no workspace ----------------
__device__ __forceinline__ void pack8(unsigned short* p, float4 a, float4 b) {
  u16x8 v;
  v[0] = f2bf(a.x); v[1] = f2bf(a.y); v[2] = f2bf(a.z); v[3] = f2bf(a.w);
  v[4] = f2bf(b.x); v[5] = f2bf(b.y); v[6] = f2bf(b.z); v[7] = f2bf(b.w);
  *(u16x8*)p = v;
}

__global__ void k_true_fb(const float* __restrict__ X, const int* __restrict__ tgt,
                          const float* __restrict__ W, const float* __restrict__ bias,
                          const float* __restrict__ tfreq, float* __restrict__ out) {
  const int n = blockIdx.x * 4 + (threadIdx.x >> 6);
  const int l = threadIdx.x & 63;
  const int tg = tgt[n];
  float4 a = ((const float4*)(X + (size_t)n * HID))[l];
  float4 wv = ((const float4*)(W + (size_t)tg * HID))[l];
  float p = a.x * wv.x + a.y * wv.y + a.z * wv.z + a.w * wv.w;
  #pragma unroll
  for (int off = 32; off > 0; off >>= 1) p += __shfl_down(p, off);
  if (l == 0) {
    out[(size_t)n * LCOLS] = p + bias[tg] - __logf(tfreq[n]);
    ((int*)out)[(size_t)NROWS * LCOLS + n] = 0;
  }
}

__global__ __launch_bounds__(256)
void k_gemm_fb(const float* __restrict__ Af, const float* __restrict__ W,
               const int* __restrict__ tgt, const int* __restrict__ sid,
               const float* __restrict__ bias, const float* __restrict__ sfreq,
               float* __restrict__ out) {
  __shared__ unsigned short sA[128 * 32];
  __shared__ unsigned short sB[128 * 32];
  const int t = threadIdx.x;
  const int w = t >> 6, l = t & 63;
  const int m0 = blockIdx.y * 128, n0 = blockIdx.x * 128;
  const int wm = w >> 1, wn = w & 1;
  f32x4 acc[4][4] = {};
  const int srow = w * 16 + (l >> 2);
  const int scol = (l & 3) * 8;

  const int id0 = sid[n0 + srow], id1 = sid[n0 + 64 + srow];
  const float* gaf0 = Af + (size_t)(m0 + srow) * HID + scol;
  const float* gaf1 = gaf0 + (size_t)64 * HID;
  const float* gbf0 = W + (size_t)id0 * HID + scol;
  const float* gbf1 = W + (size_t)id1 * HID + scol;
  for (int kk = 0; kk < HID; kk += 32) {
    float4 a0 = *(const float4*)(gaf0 + kk), a1 = *(const float4*)(gaf0 + kk + 4);
    float4 a2 = *(const float4*)(gaf1 + kk), a3 = *(const float4*)(gaf1 + kk + 4);
    float4 b0 = *(const float4*)(gbf0 + kk), b1 = *(const float4*)(gbf0 + kk + 4);
    float4 b2 = *(const float4*)(gbf1 + kk), b3 = *(const float4*)(gbf1 + kk + 4);
    __syncthreads();
    pack8(&sA[t * 8], a0, a1);
    pack8(&sA[2048 + t * 8], a2, a3);
    pack8(&sB[t * 8], b0, b1);
    pack8(&sB[2048 + t * 8], b2, b3);
    __syncthreads();
    bf16x8 af_[4], bf_[4];
    const int rl_ = l & 15, kq_ = l >> 4;
    #pragma unroll
    for (int m = 0; m < 4; m++)
      af_[m] = *(const bf16x8*)&sA[(wm * 64 + m * 16 + rl_) * 32 + kq_ * 8];
    #pragma unroll
    for (int n = 0; n < 4; n++)
      bf_[n] = *(const bf16x8*)&sB[(wn * 64 + n * 16 + rl_) * 32 + kq_ * 8];
    #pragma unroll
    for (int m = 0; m < 4; m++)
      #pragma unroll
      for (int n = 0; n < 4; n++)
        acc[m][n] = __builtin_amdgcn_mfma_f32_16x16x32_bf16(af_[m], bf_[n],
                                                            acc[m][n], 0, 0, 0);
  }
  const int rl = l & 15, rq = l >> 4;
  #pragma unroll
  for (int n = 0; n < 4; ++n) {
    const int col = n0 + wn * 64 + n * 16 + rl;
    const int sv = sid[col];
    const float sbv = bias[sv] - __logf(sfreq[col]);
    #pragma unroll
    for (int m = 0; m < 4; ++m) {
      const int rbase = m0 + wm * 64 + m * 16 + rq * 4;
      #pragma unroll
      for (int i = 0; i < 4; ++i) {
        const int r = rbase + i;
        float c = acc[m][n][i] + sbv;
        if (tgt[r] == sv) c = NEG_INF_F;
        out[(size_t)r * LCOLS + 1 + col] = c;
      }
    }
  }
}

extern "C" void kernel_launch(void* const* d_in, const int* in_sizes, int n_in,
                              void* d_out, int out_size, void* d_ws, size_t ws_size,
                              hipStream_t stream) {
  (void)in_sizes; (void)n_in; (void)out_size;
  const float* output      = (const float*)d_in[0];
  const int*   targets     = (const int*)d_in[1];
  const int*   sample_ids  = (const int*)d_in[2];
  const float* true_freq   = (const float*)d_in[3];
  const float* sample_freq = (const float*)d_in[4];
  const float* weight      = (const float*)d_in[5];
  const float* bias        = (const float*)d_in[6];
  float* out = (float*)d_out;

  const size_t needA = (size_t)NROWS * HID / 2;   // 4 MB fp4
  const size_t needB = (size_t)NSAMP * HID / 2;   // 4 MB fp4
  const bool use_ws = ws_size >= (needA + needB);

  dim3 grid(NSAMP / 128, NROWS / 128);
  if (use_ws) {
    unsigned char* Ab = (unsigned char*)d_ws;
    unsigned char* Bb = Ab + needA;
    k_prep<<<6144, 256, 0, stream>>>(output, weight, sample_ids, targets, bias,
                                     true_freq, Ab, Bb, out);
    k_gemm4<<<grid, 256, 0, stream>>>(Ab, Bb, targets, sample_ids, bias,
                                      sample_freq, out);
  } else {
    k_true_fb<<<NROWS / 4, 256, 0, stream>>>(output, targets, weight, bias,
                                             true_freq, out);
    k_gemm_fb<<<grid, 256, 0, stream>>>(output, weight, targets, sample_ids,
                                        bias, sample_freq, out);
  }
}